// Round 5
// baseline (79.681 us; speedup 1.0000x reference)
//
#include <hip/hip_runtime.h>

// RBF-MMD discriminator: B=512 rows, T=128 slabs, C=16, fp32.
// out = E_xx - 2*E_xy over per-slab RBF grams (slab weight 1 for t in {0,127},
// else 2; 254 weighted slab instances).
//
// R5 structure: R4 showed the gram main loop (not global access) is the cost
// (~1900 cyc/jt/wave vs ~400 issue model) -> MFMA->exp dependency stalls at
// 4-entry granularity. Fix: (1) software-pipeline exp of tile jt-1 against
// MFMAs of tile jt (one full j-tile of separation); (2) one gram per block,
// 2 row-tiles/wave (~80 VGPR -> 5-6 waves/SIMD); (3) Kxx symmetry: only
// strip-pairs q>=a, q>a doubled (exact; -21% entries).
//
// Split-bf16 MFMA (verified 16x16x32_bf16 layouts):
//   S = A1*B1 + A2*B2, A1=[ahi|alo] B1=[bhi|bhi], A2=[ahi|0] B2=[blo|blo]
//   (lo*lo dropped: ~2^-18 relative, zero-mean).
// Inputs pre-scaled by sqrt(log2 e); entry = exp2(dot') * 2^-gcol * 2^-grow,
// accumulated as fma(exp2(dot'), colscale, acc); row-scale in epilogue.
// (Numerics per entry identical to R4's passing kernel.)

#define LOG2E 1.4426950408889634f
#define SCALE 1.2011224087864498f   // sqrt(LOG2E)

// d_ws layout (dword offsets). [t][row][8dw] for H/L arrays, [t*512+row] scalars.
#define XH_OFF   0u
#define XL_OFF   524288u
#define YH_OFF   1048576u
#define YL_OFF   1572864u
#define GX_OFF   2097152u   // g = 0.5*log2e*|x_row|^2 (A-row scales, fp32)
#define CSX_OFF  2162688u   // 2^-g for x (column scales)
#define CSY_OFF  2228224u   // 2^-g for y
#define PART_OFF 2293760u   // 3328 floats: [0,2048) xy parts, [2048,3328) xx parts

typedef __attribute__((ext_vector_type(8))) __bf16 bf16x8;
typedef __attribute__((ext_vector_type(4))) float floatx4;

union FragU { uint4 q; unsigned int u[4]; bf16x8 v; };

// 16B-aligned group-padded LDS row offset (dwords): 8 dw/row + 4 dw pad per 4 rows.
static __device__ __forceinline__ int off(int n) { return (n << 3) + ((n >> 2) << 2); }

static __device__ __forceinline__ unsigned short bfbits(__bf16 h) {
    union { __bf16 h; unsigned short s; } u; u.h = h; return u.s;
}
static __device__ __forceinline__ unsigned int packhh(__bf16 a, __bf16 b) {
    return (unsigned int)bfbits(a) | ((unsigned int)bfbits(b) << 16);
}

// grid 512: bid>>8 = matrix (0=x,1=y), (bid>>1)&127 = t, bid&1 = row-half.
__global__ __launch_bounds__(256) void prep_kernel(const float* __restrict__ x,
                                                   const float* __restrict__ y,
                                                   unsigned int* __restrict__ ws) {
    const int bid = blockIdx.x, tid = threadIdx.x;
    const int m   = bid >> 8;
    const int t   = (bid >> 1) & 127;
    const int row = ((bid & 1) << 8) + tid;

    const float4* __restrict__ src4 = m ? (const float4*)y : (const float4*)x;
    const size_t gb = (size_t)row * 512 + t * 4;
    float4 f0 = src4[gb], f1 = src4[gb + 1], f2 = src4[gb + 2], f3 = src4[gb + 3];
    const float fs[16] = { f0.x, f0.y, f0.z, f0.w, f1.x, f1.y, f1.z, f1.w,
                           f2.x, f2.y, f2.z, f2.w, f3.x, f3.y, f3.z, f3.w };
    float g = 0.f;
    unsigned int hw[8], lw[8];
#pragma unroll
    for (int p = 0; p < 8; ++p) {
        const float v0 = fs[2 * p], v1 = fs[2 * p + 1];
        g += v0 * v0 + v1 * v1;
        const float s0 = v0 * SCALE, s1 = v1 * SCALE;
        const __bf16 h0 = (__bf16)s0, h1 = (__bf16)s1;
        hw[p] = packhh(h0, h1);
        lw[p] = packhh((__bf16)(s0 - (float)h0), (__bf16)(s1 - (float)h1));
    }
    const float gp = 0.5f * LOG2E * g;
    const unsigned int idx = (unsigned int)t * 512u + (unsigned int)row;
    unsigned int* __restrict__ H = ws + (m ? YH_OFF : XH_OFF) + (size_t)idx * 8;
    unsigned int* __restrict__ L = ws + (m ? YL_OFF : XL_OFF) + (size_t)idx * 8;
    *(uint4*)&H[0] = make_uint4(hw[0], hw[1], hw[2], hw[3]);
    *(uint4*)&H[4] = make_uint4(hw[4], hw[5], hw[6], hw[7]);
    *(uint4*)&L[0] = make_uint4(lw[0], lw[1], lw[2], lw[3]);
    *(uint4*)&L[4] = make_uint4(lw[4], lw[5], lw[6], lw[7]);
    float* __restrict__ wsf = (float*)ws;
    wsf[(m ? CSY_OFF : CSX_OFF) + idx] = __builtin_amdgcn_exp2f(-gp);
    if (!m) wsf[GX_OFF + idx] = gp;
}

// grid (26, 128): blockIdx.x = pair slot, blockIdx.y = t.
// slot<16: xy block, a=slot>>2 (A strip), q=slot&3 (col strip of Y).
// slot>=16: xx block over triangular (a,q) pairs, q>=a, weight 2 if q>a.
// Block: 4 waves, wave w owns A rows a*128 + w*32 (two 16-row tiles).
__global__ __launch_bounds__(256, 4) void gram_kernel(const unsigned int* __restrict__ ws,
                                                      float* __restrict__ part) {
    __shared__ unsigned int BH[1152], BL[1152];
    __shared__ float csB[128], srg[128];
    __shared__ float red[4];

    const int slot = blockIdx.x;
    const int t    = blockIdx.y;
    const int tid  = threadIdx.x;
    const int w    = tid >> 6;
    const int lane = tid & 63;
    const int quad = lane >> 4;
    const int l15  = lane & 15;
    const int qh   = quad & 1;
    const float* __restrict__ wsf = (const float*)ws;

    int sa, sq, isxx;
    if (slot < 16) { isxx = 0; sa = slot >> 2; sq = slot & 3; }
    else {
        isxx = 1;
        const int s = slot - 16;
        if      (s < 4) { sa = 0; sq = s; }
        else if (s < 7) { sa = 1; sq = s - 3; }
        else if (s < 9) { sa = 2; sq = s - 5; }
        else            { sa = 3; sq = 3; }
    }

    // ---- stage B-side (128 rows of X or Y) + col scales + A-row g's ----
    {
        const int r = tid & 127;
        const unsigned int base = isxx ? ((tid < 128) ? XH_OFF : XL_OFF)
                                       : ((tid < 128) ? YH_OFF : YL_OFF);
        const unsigned int* __restrict__ g =
            ws + base + (unsigned int)((t * 512 + sq * 128 + r) << 3);
        uint4 q0 = *(const uint4*)&g[0];
        uint4 q1 = *(const uint4*)&g[4];
        unsigned int* __restrict__ dst = (tid < 128) ? BH : BL;
        *(uint4*)&dst[off(r)]     = q0;
        *(uint4*)&dst[off(r) + 4] = q1;
        if (tid < 128) csB[r] = wsf[(isxx ? CSX_OFF : CSY_OFF) + t * 512 + sq * 128 + r];
        else           srg[r] = wsf[GX_OFF + t * 512 + sa * 128 + r];
    }

    // ---- A fragments: 2 row-tiles, direct uint4 loads of precomputed H/L ----
    bf16x8 a1f[2], a2f[2];
    {
        FragU z; z.q = make_uint4(0u, 0u, 0u, 0u);
        const unsigned int hbase = (quad < 2) ? XH_OFF : XL_OFF;
#pragma unroll
        for (int rt = 0; rt < 2; ++rt) {
            const int row = sa * 128 + w * 32 + rt * 16 + l15;
            const unsigned int* __restrict__ p =
                ws + hbase + (unsigned int)((t * 512 + row) << 3) + qh * 4;
            FragU u; u.q = *(const uint4*)p;
            a1f[rt] = u.v;                       // A1 = [ahi | alo]
            a2f[rt] = (quad < 2) ? u.v : z.v;    // A2 = [ahi |  0 ]
        }
    }
    __syncthreads();

    float sum[2][4] = {{0.f, 0.f, 0.f, 0.f}, {0.f, 0.f, 0.f, 0.f}};

    // ---- software-pipelined main loop: MFMA tile jt, exp tile jt-1 ----
    floatx4 accP[2], accC[2];
    float csP;
    {
        const int rb = off(l15) + qh * 4;
        FragU bh, bl;
        bh.q = *(const uint4*)&BH[rb];
        bl.q = *(const uint4*)&BL[rb];
        csP = csB[l15];
        floatx4 zc = {0.f, 0.f, 0.f, 0.f};
        accP[0] = __builtin_amdgcn_mfma_f32_16x16x32_bf16(a1f[0], bh.v, zc, 0, 0, 0);
        accP[0] = __builtin_amdgcn_mfma_f32_16x16x32_bf16(a2f[0], bl.v, accP[0], 0, 0, 0);
        accP[1] = __builtin_amdgcn_mfma_f32_16x16x32_bf16(a1f[1], bh.v, zc, 0, 0, 0);
        accP[1] = __builtin_amdgcn_mfma_f32_16x16x32_bf16(a2f[1], bl.v, accP[1], 0, 0, 0);
    }
#pragma unroll
    for (int jt = 1; jt < 8; ++jt) {
        const int n  = jt * 16 + l15;
        const int rb = off(n) + qh * 4;
        FragU bh, bl;
        bh.q = *(const uint4*)&BH[rb];
        bl.q = *(const uint4*)&BL[rb];
        const float cs = csB[n];
        floatx4 zc = {0.f, 0.f, 0.f, 0.f};
        accC[0] = __builtin_amdgcn_mfma_f32_16x16x32_bf16(a1f[0], bh.v, zc, 0, 0, 0);
        accC[0] = __builtin_amdgcn_mfma_f32_16x16x32_bf16(a2f[0], bl.v, accC[0], 0, 0, 0);
        accC[1] = __builtin_amdgcn_mfma_f32_16x16x32_bf16(a1f[1], bh.v, zc, 0, 0, 0);
        accC[1] = __builtin_amdgcn_mfma_f32_16x16x32_bf16(a2f[1], bl.v, accC[1], 0, 0, 0);
        // exp-reduce previous tile (its MFMAs retired ~a full tile ago)
#pragma unroll
        for (int rt = 0; rt < 2; ++rt)
#pragma unroll
            for (int r = 0; r < 4; ++r)
                sum[rt][r] = fmaf(__builtin_amdgcn_exp2f(accP[rt][r]), csP, sum[rt][r]);
        accP[0] = accC[0];
        accP[1] = accC[1];
        csP = cs;
    }
#pragma unroll
    for (int rt = 0; rt < 2; ++rt)
#pragma unroll
        for (int r = 0; r < 4; ++r)
            sum[rt][r] = fmaf(__builtin_amdgcn_exp2f(accP[rt][r]), csP, sum[rt][r]);

    // ---- epilogue: row-scale by 2^-g_row, then block reduction ----
    float tot = 0.f;
#pragma unroll
    for (int rt = 0; rt < 2; ++rt)
#pragma unroll
        for (int r = 0; r < 4; ++r) {
            const float rs = __builtin_amdgcn_exp2f(-srg[w * 32 + rt * 16 + quad * 4 + r]);
            tot = fmaf(sum[rt][r], rs, tot);
        }
    for (int o = 32; o > 0; o >>= 1) tot += __shfl_down(tot, o, 64);
    if (lane == 0) red[w] = tot;
    __syncthreads();
    if (tid == 0) {
        float wt = (t == 0 || t == 127) ? 1.f : 2.f;
        if (isxx && sq > sa) wt *= 2.f;   // symmetric off-diag strip-pair counted twice
        const int idx = isxx ? (2048 + t * 10 + (slot - 16)) : (t * 16 + slot);
        part[idx] = wt * (red[0] + red[1] + red[2] + red[3]);
    }
}

__global__ __launch_bounds__(256) void finalize_kernel(const float* __restrict__ part,
                                                       float* __restrict__ out) {
    const int tid = threadIdx.x;
    double vxy = 0.0, vxx = 0.0;
#pragma unroll
    for (int k = 0; k < 8; ++k)  vxy += (double)part[tid + 256 * k];      // [0,2048)
#pragma unroll
    for (int k = 8; k < 13; ++k) vxx += (double)part[tid + 256 * k];      // [2048,3328)
    for (int o = 32; o > 0; o >>= 1) {
        vxx += __shfl_down(vxx, o, 64);
        vxy += __shfl_down(vxy, o, 64);
    }
    __shared__ double red[8];
    const int wid = tid >> 6;
    if ((tid & 63) == 0) { red[wid] = vxx; red[4 + wid] = vxy; }
    __syncthreads();
    if (tid == 0) {
        double sxx = red[0] + red[1] + red[2] + red[3];
        double sxy = red[4] + red[5] + red[6] + red[7];
        // diagonal entries (~1.0 each) included in sxx: subtract 254*512
        double e1 = (sxx - 254.0 * 512.0) / (254.0 * 512.0 * 511.0);
        double e2 = sxy / (254.0 * 512.0 * 512.0);
        out[0] = (float)(e1 - 2.0 * e2);
    }
}

extern "C" void kernel_launch(void* const* d_in, const int* in_sizes, int n_in,
                              void* d_out, int out_size, void* d_ws, size_t ws_size,
                              hipStream_t stream) {
    (void)in_sizes; (void)n_in; (void)out_size; (void)ws_size;
    const float* x = (const float*)d_in[0];
    const float* y = (const float*)d_in[1];
    float* out = (float*)d_out;
    unsigned int* ws = (unsigned int*)d_ws;
    float* part = (float*)d_ws + PART_OFF;

    prep_kernel<<<dim3(512), dim3(256), 0, stream>>>(x, y, ws);
    gram_kernel<<<dim3(26, 128), dim3(256), 0, stream>>>(ws, part);
    finalize_kernel<<<dim3(1), dim3(256), 0, stream>>>(part, out);
}